// Round 11
// baseline (232.427 us; speedup 1.0000x reference)
//
#include <hip/hip_runtime.h>

constexpr int NN   = 50000;
constexpr int PADN = 50048;       // 391*128, padded rows
constexpr int KD   = 128;
constexpr int RR   = 8;
constexpr int NBKT = 196;         // dst buckets (d>>8): 196*256 = 50176 dst slots
constexpr int PADSEG = NBKT * 2048;   // 401408 segments, dst-major: seg = d*8 + r
constexpr int P4CAP = 6144;       // max edges per bucket (mean 4083, +32sigma)

typedef __attribute__((ext_vector_type(8))) short short8;
typedef __attribute__((ext_vector_type(4))) float f32x4;
typedef __attribute__((ext_vector_type(4))) unsigned int u32x4;

__device__ __forceinline__ float bflo(unsigned u){ return __uint_as_float(u << 16); }
__device__ __forceinline__ float bfhi(unsigned u){ return __uint_as_float(u & 0xffff0000u); }
__device__ __forceinline__ unsigned pk_bf16(float a, float b){
  unsigned ua = __float_as_uint(a), ub = __float_as_uint(b);
  ua = (ua + 0x7fffu + ((ua >> 16) & 1u)) >> 16;
  ub = (ub + 0x7fffu + ((ub >> 16) & 1u)) & 0xffff0000u;
  return (ua & 0xffffu) | ub;
}
__device__ __forceinline__ unsigned short bf1(float a){
  unsigned ua = __float_as_uint(a);
  return (unsigned short)((ua + 0x7fffu + ((ua >> 16) & 1u)) >> 16);
}

// ---------------- convert x to padded bf16 ----------------
__global__ __launch_bounds__(256)
void convert_x(const float* __restrict__ x, unsigned* __restrict__ xb) {
  const int idx = blockIdx.x * 256 + threadIdx.x;   // one per 8 elems
  if (idx >= PADN * 16) return;
  const int row = idx >> 4, o = (idx & 15) * 8;
  uint4 v = make_uint4(0u, 0u, 0u, 0u);
  if (row < NN) {
    float4 a = *(const float4*)&x[(size_t)row * KD + o];
    float4 b = *(const float4*)&x[(size_t)row * KD + o + 4];
    v.x = pk_bf16(a.x, a.y); v.y = pk_bf16(a.z, a.w);
    v.z = pk_bf16(b.x, b.y); v.w = pk_bf16(b.z, b.w);
  }
  *(uint4*)&xb[(size_t)idx * 4] = v;
}

// ---------------- P1: coarse histogram, TRANSPOSED output hist[bucket][block] ----
__global__ __launch_bounds__(256)
void p1_hist(const int* __restrict__ dst, int E, int NBE, int* __restrict__ hist) {
  __shared__ int h[256];
  const int t = threadIdx.x;
  h[t] = 0;
  __syncthreads();
  const int base = blockIdx.x * 2048;
#pragma unroll
  for (int k = 0; k < 8; ++k) {
    const int e = base + k * 256 + t;
    if (e < E) atomicAdd(&h[dst[e] >> 8], 1);
  }
  __syncthreads();
  hist[t * NBE + blockIdx.x] = h[t];
}

// ---------------- P2: scan (single block; sequential per-thread reads) ----------------
__global__ __launch_bounds__(256)
void p2_scan(int* __restrict__ hist, int NBE,
             int* __restrict__ bktBase, int* __restrict__ bktCnt) {
  const int t = threadIdx.x;
  int* row = hist + (size_t)t * NBE;
  int sum = 0;
#pragma unroll 8
  for (int blk = 0; blk < NBE; ++blk) sum += row[blk];
  // exclusive scan of bucket totals across 256 threads
  int inc = sum;
#pragma unroll
  for (int o = 1; o < 64; o <<= 1) {
    int v = __shfl_up(inc, o);
    if ((t & 63) >= o) inc += v;
  }
  __shared__ int wsum[4];
  if ((t & 63) == 63) wsum[t >> 6] = inc;
  __syncthreads();
  int wpre = 0;
#pragma unroll
  for (int w = 0; w < 4; ++w) if (w < (t >> 6)) wpre += wsum[w];
  const int excl = wpre + inc - sum;
  bktBase[t] = excl;
  bktCnt[t]  = sum;
  // rewrite hist row to running global bases
  int run = excl;
#pragma unroll 8
  for (int blk = 0; blk < NBE; ++blk) {
    const int c = row[blk];
    row[blk] = run;
    run += c;
  }
}

// ---------------- P3: partition edges into bucket-ordered ebuf ----------------
__global__ __launch_bounds__(256)
void p3_part(const int* __restrict__ src, const int* __restrict__ dst,
             const int* __restrict__ et, int E, int NBE,
             const int* __restrict__ hist, uint2* __restrict__ ebuf) {
  __shared__ int cur[256];
  const int t = threadIdx.x;
  cur[t] = hist[t * NBE + blockIdx.x];
  __syncthreads();
  const int base = blockIdx.x * 2048;
#pragma unroll
  for (int k = 0; k < 8; ++k) {
    const int e = base + k * 256 + t;
    if (e < E) {
      const int d = dst[e];
      const int pos = atomicAdd(&cur[d >> 8], 1);
      ebuf[pos] = make_uint2((unsigned)src[e], (unsigned)(d * 8 + et[e]));
    }
  }
}

// ---------------- P4: per-bucket fine count + scan + scatter (one block/bucket) ----
__global__ __launch_bounds__(256)
void p4_build(const uint2* __restrict__ ebuf,
              const int* __restrict__ bktBase, const int* __restrict__ bktCnt,
              int* __restrict__ fillpos, int* __restrict__ cntarr,
              int* __restrict__ srt) {
  __shared__ uint2 eL[P4CAP];     // 48 KB
  __shared__ int   cL[2048];      // 8 KB: counts, then local prefixes
  __shared__ int   wsum[4];
  const int b = blockIdx.x, t = threadIdx.x;
  const int base0 = bktBase[b];
  int n = bktCnt[b];
  if (n > P4CAP) n = P4CAP;       // safety clamp (statistically unreachable)
  const int seg0 = b * 2048;

#pragma unroll
  for (int j = 0; j < 8; ++j) cL[t * 8 + j] = 0;
  __syncthreads();

  // load edges to LDS + rank within segment
  for (int i = t; i < n; i += 256) {
    uint2 e = ebuf[base0 + i];
    const int sl = (int)e.y - seg0;          // 0..2047
    const int rk = atomicAdd(&cL[sl], 1);
    e.y = (unsigned)(sl | (rk << 11));       // sl:11 bits, rk:<=13 bits
    eL[i] = e;
  }
  __syncthreads();

  // block scan over the 2048 per-segment counts (8 per thread)
  int c8[8], tsum = 0;
#pragma unroll
  for (int j = 0; j < 8; ++j) { c8[j] = cL[t * 8 + j]; tsum += c8[j]; }
  int inc = tsum;
#pragma unroll
  for (int o = 1; o < 64; o <<= 1) {
    int v = __shfl_up(inc, o);
    if ((t & 63) >= o) inc += v;
  }
  if ((t & 63) == 63) wsum[t >> 6] = inc;
  __syncthreads();
  int wpre = 0;
#pragma unroll
  for (int w = 0; w < 4; ++w) if (w < (t >> 6)) wpre += wsum[w];
  int run = wpre + inc - tsum;
  int o8[8];
#pragma unroll
  for (int j = 0; j < 8; ++j) { o8[j] = run; run += c8[j]; }

  // write global per-segment base + count; stash local prefix in cL
  const int gs = seg0 + t * 8;
  *(int4*)&fillpos[gs]     = make_int4(base0 + o8[0], base0 + o8[1], base0 + o8[2], base0 + o8[3]);
  *(int4*)&fillpos[gs + 4] = make_int4(base0 + o8[4], base0 + o8[5], base0 + o8[6], base0 + o8[7]);
  *(int4*)&cntarr[gs]      = make_int4(c8[0], c8[1], c8[2], c8[3]);
  *(int4*)&cntarr[gs + 4]  = make_int4(c8[4], c8[5], c8[6], c8[7]);
#pragma unroll
  for (int j = 0; j < 8; ++j) cL[t * 8 + j] = o8[j];
  __syncthreads();

  // scatter srcs into segment-sorted srt (within this bucket's window)
  for (int i = t; i < n; i += 256) {
    const uint2 e = eL[i];
    const int sl = (int)(e.y & 2047u);
    const int rk = (int)(e.y >> 11);
    srt[base0 + cL[sl] + rk] = (int)e.x;
  }
}

// Wt1[9][128][128] and Wt2[9][64][128] bf16, transposed, in one dispatch
__global__ __launch_bounds__(256)
void prep_w(const float* __restrict__ W1, const float* __restrict__ root1,
            const float* __restrict__ W2, const float* __restrict__ root2,
            unsigned short* __restrict__ Wt1, unsigned short* __restrict__ Wt2) {
  int idx = blockIdx.x * 256 + threadIdx.x;
  if (idx < 9 * 128 * KD) {
    const int k = idx & 127;
    const int n = (idx >> 7) & 127;
    const int ch = idx >> 14;
    const float v = (ch < 8) ? W1[((size_t)ch * KD + k) * 128 + n] : root1[(size_t)k * 128 + n];
    Wt1[idx] = bf1(v);
  } else {
    idx -= 9 * 128 * KD;
    const int k = idx & 127;
    const int n = (idx >> 7) & 63;
    const int ch = idx >> 13;
    const float v = (ch < 8) ? W2[((size_t)ch * KD + k) * 64 + n] : root2[(size_t)k * 64 + n];
    Wt2[idx] = bf1(v);
  }
}

// ---------------- layer-1 gather: dst-major agg[d][r][:] = mean of bf16 X rows ----
// 16 lanes per segment (seg = d*8+r); fully contiguous NT write stream
__global__ __launch_bounds__(256)
void gather_mean(const unsigned* __restrict__ Xb,         // [PADN][64] uint
                 const int* __restrict__ srt,
                 const int* __restrict__ fillpos, const int* __restrict__ cntarr,
                 unsigned* __restrict__ agg) {            // [PADN][8][64] uint
  const int g = blockIdx.x * 16 + (threadIdx.x >> 4);     // seg = d*8 + r
  const int lane = threadIdx.x & 15;
  const int c = cntarr[g];
  const int base = fillpos[g];
  float acc[8] = {};
  int i = 0;
  for (; i + 1 < c; i += 2) {
    const int s0 = srt[base + i], s1 = srt[base + i + 1];
    const uint4 v0 = *(const uint4*)&Xb[(size_t)s0 * 64 + lane * 4];
    const uint4 v1 = *(const uint4*)&Xb[(size_t)s1 * 64 + lane * 4];
    acc[0] += bflo(v0.x) + bflo(v1.x); acc[1] += bfhi(v0.x) + bfhi(v1.x);
    acc[2] += bflo(v0.y) + bflo(v1.y); acc[3] += bfhi(v0.y) + bfhi(v1.y);
    acc[4] += bflo(v0.z) + bflo(v1.z); acc[5] += bfhi(v0.z) + bfhi(v1.z);
    acc[6] += bflo(v0.w) + bflo(v1.w); acc[7] += bfhi(v0.w) + bfhi(v1.w);
  }
  if (i < c) {
    const uint4 v0 = *(const uint4*)&Xb[(size_t)srt[base + i] * 64 + lane * 4];
    acc[0] += bflo(v0.x); acc[1] += bfhi(v0.x);
    acc[2] += bflo(v0.y); acc[3] += bfhi(v0.y);
    acc[4] += bflo(v0.z); acc[5] += bfhi(v0.z);
    acc[6] += bflo(v0.w); acc[7] += bfhi(v0.w);
  }
  const float sc = (c > 0) ? 1.0f / (float)c : 0.0f;
  u32x4 o;
  o.x = pk_bf16(acc[0] * sc, acc[1] * sc); o.y = pk_bf16(acc[2] * sc, acc[3] * sc);
  o.z = pk_bf16(acc[4] * sc, acc[5] * sc); o.w = pk_bf16(acc[6] * sc, acc[7] * sc);
  __builtin_nontemporal_store(o, (u32x4*)&agg[(size_t)g * 64 + lane * 4]);
}

// ---------------- layer-1 MFMA GEMM ----------------
// hb = relu(sum_{ch<8} agg[:,ch,:] @ Wt_ch^T + xb @ Wt_8^T + bias), bf16 out, pad zeroed
__global__ __launch_bounds__(256)
void rgcn_gemm_mfma(const unsigned short* __restrict__ agg,   // [PADN][8][128] bf16
                    const unsigned short* __restrict__ xrow,  // [PADN][128] bf16
                    const unsigned short* __restrict__ Wt,    // [9][128][128] bf16
                    const float* __restrict__ bias,
                    unsigned short* __restrict__ Cout) {
  constexpr int BN = 128, WM = 64, MF = 4, NF = 4, WAVES_N = 2;
  __shared__ uint4 ldsv[(128 * 128 + BN * 128) / 16];
  char* As = (char*)ldsv;
  char* Bs = (char*)ldsv + 128 * 128;

  const int t = threadIdx.x;
  const int l = t & 63;
  const int w = t >> 6;
  const int wr = w / WAVES_N;
  const int wc = w % WAVES_N;
  const int row0 = blockIdx.x * 128;
  const int l15 = l & 15, lq = l >> 4;

  f32x4 acc[MF][NF];
#pragma unroll
  for (int mi = 0; mi < MF; ++mi)
#pragma unroll
    for (int ni = 0; ni < NF; ++ni) acc[mi][ni] = (f32x4){0.f, 0.f, 0.f, 0.f};

  for (int ch = 0; ch < 9; ++ch) {
    const unsigned short* bP = Wt + (size_t)ch * BN * KD;
#pragma unroll
    for (int kt = 0; kt < 2; ++kt) {
      __syncthreads();
#pragma unroll
      for (int i = 0; i < 4; ++i) {
        const int s = t + i * 256;
        const int r = s >> 3, c16 = s & 7;
        const unsigned short* ap = (ch < 8)
            ? (agg + ((size_t)(row0 + r) * 8 + ch) * KD + kt * 64 + c16 * 8)
            : (xrow + (size_t)(row0 + r) * KD + kt * 64 + c16 * 8);
        u32x4 v = __builtin_nontemporal_load((const u32x4*)ap);
        *(u32x4*)(As + r * 128 + ((c16 ^ (r & 7)) * 16)) = v;
      }
#pragma unroll
      for (int i = 0; i < BN / 32; ++i) {
        const int s = t + i * 256;
        const int r = s >> 3, c16 = s & 7;
        uint4 v = *(const uint4*)(bP + (size_t)r * KD + kt * 64 + c16 * 8);
        *(uint4*)(Bs + r * 128 + ((c16 ^ (r & 7)) * 16)) = v;
      }
      __syncthreads();
#pragma unroll
      for (int ks = 0; ks < 2; ++ks) {
        short8 bfr[NF];
#pragma unroll
        for (int ni = 0; ni < NF; ++ni) {
          const int br = wc * 64 + ni * 16 + l15;
          bfr[ni] = *(const short8*)(Bs + br * 128 + (((ks * 4 + lq) ^ (br & 7)) * 16));
        }
#pragma unroll
        for (int mi = 0; mi < MF; ++mi) {
          const int ar = wr * WM + mi * 16 + l15;
          short8 af = *(const short8*)(As + ar * 128 + (((ks * 4 + lq) ^ (ar & 7)) * 16));
#pragma unroll
          for (int ni = 0; ni < NF; ++ni)
            acc[mi][ni] = __builtin_amdgcn_mfma_f32_16x16x32_bf16(af, bfr[ni], acc[mi][ni], 0, 0, 0);
        }
      }
    }
  }
#pragma unroll
  for (int ni = 0; ni < NF; ++ni) {
    const int col = wc * 64 + ni * 16 + l15;
    const float bv = bias[col];
#pragma unroll
    for (int mi = 0; mi < MF; ++mi) {
#pragma unroll
      for (int q = 0; q < 4; ++q) {
        const int grow = row0 + wr * WM + mi * 16 + lq * 4 + q;
        if (grow < NN) {
          float v = fmaxf(acc[mi][ni][q] + bv, 0.f);
          Cout[(size_t)grow * BN + col] = bf1(v);
        } else {
          Cout[(size_t)grow * BN + col] = 0;   // clean pad rows for gemm_y
        }
      }
    }
  }
}

// ---------------- layer-2 transform GEMM: Y[M,576] = hb[M,128] @ Wt2^T ----------------
__global__ __launch_bounds__(256)
void gemm_y(const unsigned short* __restrict__ A,    // [PADN][128] bf16
            const unsigned short* __restrict__ Wt,   // [576][128] bf16
            unsigned short* __restrict__ Y) {        // [PADN][576] bf16
  constexpr int BN = 64, NCOLS = 576, WM = 32, MF = 2, NF = 4;
  __shared__ uint4 ldsv[(128 * 128 + BN * 128) / 16];
  char* As = (char*)ldsv;
  char* Bs = (char*)ldsv + 128 * 128;

  const int t = threadIdx.x;
  const int l = t & 63;
  const int w = t >> 6;
  const int row0 = blockIdx.x * 128;
  const int col0 = blockIdx.y * BN;
  const unsigned short* bP = Wt + (size_t)col0 * KD;
  const int l15 = l & 15, lq = l >> 4;

  f32x4 acc[MF][NF];
#pragma unroll
  for (int mi = 0; mi < MF; ++mi)
#pragma unroll
    for (int ni = 0; ni < NF; ++ni) acc[mi][ni] = (f32x4){0.f, 0.f, 0.f, 0.f};

#pragma unroll
  for (int kt = 0; kt < 2; ++kt) {
    __syncthreads();
#pragma unroll
    for (int i = 0; i < 4; ++i) {
      const int s = t + i * 256;
      const int r = s >> 3, c16 = s & 7;
      uint4 v = *(const uint4*)(A + (size_t)(row0 + r) * KD + kt * 64 + c16 * 8);
      *(uint4*)(As + r * 128 + ((c16 ^ (r & 7)) * 16)) = v;
    }
#pragma unroll
    for (int i = 0; i < BN / 32; ++i) {
      const int s = t + i * 256;
      const int r = s >> 3, c16 = s & 7;
      uint4 v = *(const uint4*)(bP + (size_t)r * KD + kt * 64 + c16 * 8);
      *(uint4*)(Bs + r * 128 + ((c16 ^ (r & 7)) * 16)) = v;
    }
    __syncthreads();
#pragma unroll
    for (int ks = 0; ks < 2; ++ks) {
      short8 bfr[NF];
#pragma unroll
      for (int ni = 0; ni < NF; ++ni) {
        const int br = ni * 16 + l15;
        bfr[ni] = *(const short8*)(Bs + br * 128 + (((ks * 4 + lq) ^ (br & 7)) * 16));
      }
#pragma unroll
      for (int mi = 0; mi < MF; ++mi) {
        const int ar = w * WM + mi * 16 + l15;
        short8 af = *(const short8*)(As + ar * 128 + (((ks * 4 + lq) ^ (ar & 7)) * 16));
#pragma unroll
        for (int ni = 0; ni < NF; ++ni)
          acc[mi][ni] = __builtin_amdgcn_mfma_f32_16x16x32_bf16(af, bfr[ni], acc[mi][ni], 0, 0, 0);
      }
    }
  }
#pragma unroll
  for (int ni = 0; ni < NF; ++ni) {
    const int col = col0 + ni * 16 + l15;
#pragma unroll
    for (int mi = 0; mi < MF; ++mi) {
#pragma unroll
      for (int q = 0; q < 4; ++q) {
        const int grow = row0 + w * WM + mi * 16 + lq * 4 + q;
        Y[(size_t)grow * NCOLS + col] = bf1(acc[mi][ni][q]);
      }
    }
  }
}

// ---------------- layer-2 gather-reduce: out[d] = self + bias + sum_r mean_r ----
// 16 lanes per dst node, FO=64, fp32 out.
__global__ __launch_bounds__(256)
void gather_out(const unsigned* __restrict__ Y,      // [PADN][288] uints
                const int* __restrict__ srt,
                const int* __restrict__ fillpos, const int* __restrict__ cntarr,
                const float* __restrict__ bias,
                float* __restrict__ Out) {
  const int d = blockIdx.x * 16 + (threadIdx.x >> 4);
  const int lane = threadIdx.x & 15;
  const int l = threadIdx.x & 63;
  const int g16 = l & 48;

  // lanes 0..7: segment base for r=lane; lanes 8..15: count for r=lane-8
  const int meta = (lane < 8) ? fillpos[d * 8 + lane] : cntarr[d * 8 + (lane - 8)];

  float acc[4] = {};
#pragma unroll
  for (int r = 0; r < 8; ++r) {
    const int base = __shfl(meta, g16 + r);
    const int c    = __shfl(meta, g16 + 8 + r);
    float tmp[4] = {};
    int i = 0;
    for (; i + 1 < c; i += 2) {
      const int s0 = srt[base + i], s1 = srt[base + i + 1];
      const uint2 v0 = *(const uint2*)&Y[(size_t)s0 * 288 + r * 32 + lane * 2];
      const uint2 v1 = *(const uint2*)&Y[(size_t)s1 * 288 + r * 32 + lane * 2];
      tmp[0] += bflo(v0.x) + bflo(v1.x); tmp[1] += bfhi(v0.x) + bfhi(v1.x);
      tmp[2] += bflo(v0.y) + bflo(v1.y); tmp[3] += bfhi(v0.y) + bfhi(v1.y);
    }
    if (i < c) {
      const uint2 v0 = *(const uint2*)&Y[(size_t)srt[base + i] * 288 + r * 32 + lane * 2];
      tmp[0] += bflo(v0.x); tmp[1] += bfhi(v0.x);
      tmp[2] += bflo(v0.y); tmp[3] += bfhi(v0.y);
    }
    const float inv = (c > 0) ? 1.0f / (float)c : 0.0f;
#pragma unroll
    for (int j = 0; j < 4; ++j) acc[j] += tmp[j] * inv;
  }

  // self slice (ch 8) + bias
  const uint2 sv = *(const uint2*)&Y[(size_t)d * 288 + 256 + lane * 2];
  const float4 b0 = *(const float4*)&bias[lane * 4];
  float4 o;
  o.x = bflo(sv.x) + b0.x + acc[0];
  o.y = bfhi(sv.x) + b0.y + acc[1];
  o.z = bflo(sv.y) + b0.z + acc[2];
  o.w = bfhi(sv.y) + b0.w + acc[3];
  *(float4*)&Out[(size_t)d * 64 + lane * 4] = o;
}

// ---------------- launch ----------------
extern "C" void kernel_launch(void* const* d_in, const int* in_sizes, int n_in,
                              void* d_out, int out_size, void* d_ws, size_t ws_size,
                              hipStream_t stream) {
  const float* x     = (const float*)d_in[0];
  const int*   ei    = (const int*)d_in[1];
  const int*   et    = (const int*)d_in[2];
  const float* W1    = (const float*)d_in[3];
  const float* root1 = (const float*)d_in[4];
  const float* b1    = (const float*)d_in[5];
  const float* W2    = (const float*)d_in[6];
  const float* root2 = (const float*)d_in[7];
  const float* b2    = (const float*)d_in[8];
  float* out = (float*)d_out;

  const int E = in_sizes[2];
  const int* src  = ei;
  const int* dstv = ei + E;

  // workspace layout (~135.5 MB, 16B-aligned)
  char* ws = (char*)d_ws;
  unsigned short* xb  = (unsigned short*)ws;                 // 12,812,288 B
  unsigned short* hb  = (unsigned short*)(ws + 12812288);    // 12,812,288 B
  unsigned short* agg = (unsigned short*)(ws + 25624576);    // 102,498,304 B (ebuf/Y2 alias)
  unsigned short* Wt1 = (unsigned short*)(ws + 128122880);   //    294,912 B
  unsigned short* Wt2 = (unsigned short*)(ws + 128417792);   //    147,456 B
  int* fillpos = (int*)(ws + 128565248);                     // PADSEG*4 = 1,605,632 B
  int* cntarr  = (int*)(ws + 130170880);                     // PADSEG*4 = 1,605,632 B
  int* srt     = (int*)(ws + 131776512);                     //  3,200,000 B
  int* hist    = (int*)(ws + 134976512);                     //    524,288 B (256*NBE*4)
  int* bktBase = (int*)(ws + 135500800);                     //      1,024 B
  int* bktCnt  = (int*)(ws + 135501824);                     //      1,024 B
  uint2* ebuf  = (uint2*)agg;   // 6.4 MB, dead before agg is written

  const int NBE = (E + 2047) / 2048;   // 392 for E=800000

  // structure build: hist -> scan -> partition -> per-bucket build (no global atomics)
  convert_x<<<PADN * 16 / 256, 256, 0, stream>>>(x, (unsigned*)xb);
  p1_hist<<<NBE, 256, 0, stream>>>(dstv, E, NBE, hist);
  p2_scan<<<1, 256, 0, stream>>>(hist, NBE, bktBase, bktCnt);
  p3_part<<<NBE, 256, 0, stream>>>(src, dstv, et, E, NBE, hist, ebuf);
  p4_build<<<NBKT, 256, 0, stream>>>(ebuf, bktBase, bktCnt, fillpos, cntarr, srt);

  prep_w<<<(9 * 128 * KD + 9 * 64 * KD) / 256, 256, 0, stream>>>(W1, root1, W2, root2, Wt1, Wt2);

  const int mBlocks = PADN / 128;       // 391

  // layer 1: aggregate-then-transform (dst-major agg path); grid covers PADN rows
  gather_mean<<<PADN * 8 / 16, 256, 0, stream>>>((const unsigned*)xb, srt, fillpos, cntarr, (unsigned*)agg);
  rgcn_gemm_mfma<<<mBlocks, 256, 0, stream>>>(agg, xb, Wt1, b1, hb);

  // layer 2: transform-then-aggregate (Y path, straight to out)
  unsigned short* Y2 = agg;
  gemm_y<<<dim3(mBlocks, 9), 256, 0, stream>>>(hb, Wt2, Y2);
  gather_out<<<NN / 16, 256, 0, stream>>>((const unsigned*)Y2, srt, fillpos, cntarr, b2, out);
}

// Round 12
// 230.567 us; speedup vs baseline: 1.0081x; 1.0081x over previous
//
#include <hip/hip_runtime.h>

constexpr int NN   = 50000;
constexpr int PADN = 50048;       // 391*128, padded rows
constexpr int KD   = 128;
constexpr int RR   = 8;
constexpr int NSEG = RR * NN;     // 400000 live segments (seg = d*8 + r)
constexpr int NBKT = 196;         // dst buckets (d>>8): 196*256 = 50176 dst slots
constexpr int PADSEG = NBKT * 2048;   // 401408 segments
constexpr int P4CAP = 6144;       // max edges per bucket (mean 4083)

typedef __attribute__((ext_vector_type(8))) short short8;
typedef __attribute__((ext_vector_type(4))) float f32x4;
typedef __attribute__((ext_vector_type(4))) unsigned int u32x4;

__device__ __forceinline__ float bflo(unsigned u){ return __uint_as_float(u << 16); }
__device__ __forceinline__ float bfhi(unsigned u){ return __uint_as_float(u & 0xffff0000u); }
__device__ __forceinline__ unsigned pk_bf16(float a, float b){
  unsigned ua = __float_as_uint(a), ub = __float_as_uint(b);
  ua = (ua + 0x7fffu + ((ua >> 16) & 1u)) >> 16;
  ub = (ub + 0x7fffu + ((ub >> 16) & 1u)) & 0xffff0000u;
  return (ua & 0xffffu) | ub;
}
__device__ __forceinline__ unsigned short bf1(float a){
  unsigned ua = __float_as_uint(a);
  return (unsigned short)((ua + 0x7fffu + ((ua >> 16) & 1u)) >> 16);
}

// ---------------- convert x to padded bf16 ----------------
__global__ __launch_bounds__(256)
void convert_x(const float* __restrict__ x, unsigned* __restrict__ xb) {
  const int idx = blockIdx.x * 256 + threadIdx.x;   // one per 8 elems
  if (idx >= PADN * 16) return;
  const int row = idx >> 4, o = (idx & 15) * 8;
  uint4 v = make_uint4(0u, 0u, 0u, 0u);
  if (row < NN) {
    float4 a = *(const float4*)&x[(size_t)row * KD + o];
    float4 b = *(const float4*)&x[(size_t)row * KD + o + 4];
    v.x = pk_bf16(a.x, a.y); v.y = pk_bf16(a.z, a.w);
    v.z = pk_bf16(b.x, b.y); v.w = pk_bf16(b.z, b.w);
  }
  *(uint4*)&xb[(size_t)idx * 4] = v;
}

// ---------------- P1: coarse histogram, TRANSPOSED output hist[bucket][block] ----
__global__ __launch_bounds__(256)
void p1_hist(const int* __restrict__ dst, int E, int NBE, int* __restrict__ hist) {
  __shared__ int h[256];
  const int t = threadIdx.x;
  h[t] = 0;
  __syncthreads();
  const int base = blockIdx.x * 2048;
#pragma unroll
  for (int k = 0; k < 8; ++k) {
    const int e = base + k * 256 + t;
    if (e < E) atomicAdd(&h[dst[e] >> 8], 1);
  }
  __syncthreads();
  hist[t * NBE + blockIdx.x] = h[t];
}

// ---------------- P2: scan (single block; sequential per-thread reads) ----------------
__global__ __launch_bounds__(256)
void p2_scan(int* __restrict__ hist, int NBE,
             int* __restrict__ bktBase, int* __restrict__ bktCnt) {
  const int t = threadIdx.x;
  int* row = hist + (size_t)t * NBE;
  int sum = 0;
#pragma unroll 8
  for (int blk = 0; blk < NBE; ++blk) sum += row[blk];
  int inc = sum;
#pragma unroll
  for (int o = 1; o < 64; o <<= 1) {
    int v = __shfl_up(inc, o);
    if ((t & 63) >= o) inc += v;
  }
  __shared__ int wsum[4];
  if ((t & 63) == 63) wsum[t >> 6] = inc;
  __syncthreads();
  int wpre = 0;
#pragma unroll
  for (int w = 0; w < 4; ++w) if (w < (t >> 6)) wpre += wsum[w];
  const int excl = wpre + inc - sum;
  bktBase[t] = excl;
  bktCnt[t]  = sum;
  int run = excl;
#pragma unroll 8
  for (int blk = 0; blk < NBE; ++blk) {
    const int c = row[blk];
    row[blk] = run;
    run += c;
  }
}

// ---------------- P3: partition edges into bucket-ordered ebuf ----------------
__global__ __launch_bounds__(256)
void p3_part(const int* __restrict__ src, const int* __restrict__ dst,
             const int* __restrict__ et, int E, int NBE,
             const int* __restrict__ hist, uint2* __restrict__ ebuf) {
  __shared__ int cur[256];
  const int t = threadIdx.x;
  cur[t] = hist[t * NBE + blockIdx.x];
  __syncthreads();
  const int base = blockIdx.x * 2048;
#pragma unroll
  for (int k = 0; k < 8; ++k) {
    const int e = base + k * 256 + t;
    if (e < E) {
      const int d = dst[e];
      const int pos = atomicAdd(&cur[d >> 8], 1);
      ebuf[pos] = make_uint2((unsigned)src[e], (unsigned)(d * 8 + et[e]));
    }
  }
}

// ---------------- P4: per-bucket fine count + scan + scatter (one block/bucket) ----
__global__ __launch_bounds__(256)
void p4_build(const uint2* __restrict__ ebuf,
              const int* __restrict__ bktBase, const int* __restrict__ bktCnt,
              int* __restrict__ fillpos, int* __restrict__ cntarr,
              int* __restrict__ srt) {
  __shared__ uint2 eL[P4CAP];     // 48 KB
  __shared__ int   cL[2048];      // 8 KB
  __shared__ int   wsum[4];
  const int b = blockIdx.x, t = threadIdx.x;
  const int base0 = bktBase[b];
  int n = bktCnt[b];
  if (n > P4CAP) n = P4CAP;
  const int seg0 = b * 2048;

#pragma unroll
  for (int j = 0; j < 8; ++j) cL[t * 8 + j] = 0;
  __syncthreads();

  for (int i = t; i < n; i += 256) {
    uint2 e = ebuf[base0 + i];
    const int sl = (int)e.y - seg0;
    const int rk = atomicAdd(&cL[sl], 1);
    e.y = (unsigned)(sl | (rk << 11));
    eL[i] = e;
  }
  __syncthreads();

  int c8[8], tsum = 0;
#pragma unroll
  for (int j = 0; j < 8; ++j) { c8[j] = cL[t * 8 + j]; tsum += c8[j]; }
  int inc = tsum;
#pragma unroll
  for (int o = 1; o < 64; o <<= 1) {
    int v = __shfl_up(inc, o);
    if ((t & 63) >= o) inc += v;
  }
  if ((t & 63) == 63) wsum[t >> 6] = inc;
  __syncthreads();
  int wpre = 0;
#pragma unroll
  for (int w = 0; w < 4; ++w) if (w < (t >> 6)) wpre += wsum[w];
  int run = wpre + inc - tsum;
  int o8[8];
#pragma unroll
  for (int j = 0; j < 8; ++j) { o8[j] = run; run += c8[j]; }

  const int gs = seg0 + t * 8;
  *(int4*)&fillpos[gs]     = make_int4(base0 + o8[0], base0 + o8[1], base0 + o8[2], base0 + o8[3]);
  *(int4*)&fillpos[gs + 4] = make_int4(base0 + o8[4], base0 + o8[5], base0 + o8[6], base0 + o8[7]);
  *(int4*)&cntarr[gs]      = make_int4(c8[0], c8[1], c8[2], c8[3]);
  *(int4*)&cntarr[gs + 4]  = make_int4(c8[4], c8[5], c8[6], c8[7]);
#pragma unroll
  for (int j = 0; j < 8; ++j) cL[t * 8 + j] = o8[j];
  __syncthreads();

  for (int i = t; i < n; i += 256) {
    const uint2 e = eL[i];
    const int sl = (int)(e.y & 2047u);
    const int rk = (int)(e.y >> 11);
    srt[base0 + cL[sl] + rk] = (int)e.x;
  }
}

// Wt1[9][128][128] and Wt2[9][64][128] bf16, transposed, in one dispatch
__global__ __launch_bounds__(256)
void prep_w(const float* __restrict__ W1, const float* __restrict__ root1,
            const float* __restrict__ W2, const float* __restrict__ root2,
            unsigned short* __restrict__ Wt1, unsigned short* __restrict__ Wt2) {
  int idx = blockIdx.x * 256 + threadIdx.x;
  if (idx < 9 * 128 * KD) {
    const int k = idx & 127;
    const int n = (idx >> 7) & 127;
    const int ch = idx >> 14;
    const float v = (ch < 8) ? W1[((size_t)ch * KD + k) * 128 + n] : root1[(size_t)k * 128 + n];
    Wt1[idx] = bf1(v);
  } else {
    idx -= 9 * 128 * KD;
    const int k = idx & 127;
    const int n = (idx >> 7) & 63;
    const int ch = idx >> 13;
    const float v = (ch < 8) ? W2[((size_t)ch * KD + k) * 64 + n] : root2[(size_t)k * 64 + n];
    Wt2[idx] = bf1(v);
  }
}

// ---------------- layer-1 gather: relation-major agg[r][d][:] ----------------
// 16 lanes per segment (seg = d*8+r); NT store
__global__ __launch_bounds__(256)
void gather_mean(const unsigned* __restrict__ Xb,         // [PADN][64] uint
                 const int* __restrict__ srt,
                 const int* __restrict__ fillpos, const int* __restrict__ cntarr,
                 unsigned* __restrict__ agg) {            // [8][PADN][64] uint
  const int g = blockIdx.x * 16 + (threadIdx.x >> 4);     // seg = d*8 + r
  const int lane = threadIdx.x & 15;
  const int c = cntarr[g];
  const int base = fillpos[g];
  float acc[8] = {};
  int i = 0;
  for (; i + 1 < c; i += 2) {
    const int s0 = srt[base + i], s1 = srt[base + i + 1];
    const uint4 v0 = *(const uint4*)&Xb[(size_t)s0 * 64 + lane * 4];
    const uint4 v1 = *(const uint4*)&Xb[(size_t)s1 * 64 + lane * 4];
    acc[0] += bflo(v0.x) + bflo(v1.x); acc[1] += bfhi(v0.x) + bfhi(v1.x);
    acc[2] += bflo(v0.y) + bflo(v1.y); acc[3] += bfhi(v0.y) + bfhi(v1.y);
    acc[4] += bflo(v0.z) + bflo(v1.z); acc[5] += bfhi(v0.z) + bfhi(v1.z);
    acc[6] += bflo(v0.w) + bflo(v1.w); acc[7] += bfhi(v0.w) + bfhi(v1.w);
  }
  if (i < c) {
    const uint4 v0 = *(const uint4*)&Xb[(size_t)srt[base + i] * 64 + lane * 4];
    acc[0] += bflo(v0.x); acc[1] += bfhi(v0.x);
    acc[2] += bflo(v0.y); acc[3] += bfhi(v0.y);
    acc[4] += bflo(v0.z); acc[5] += bfhi(v0.z);
    acc[6] += bflo(v0.w); acc[7] += bfhi(v0.w);
  }
  const float sc = (c > 0) ? 1.0f / (float)c : 0.0f;
  u32x4 o;
  o.x = pk_bf16(acc[0] * sc, acc[1] * sc); o.y = pk_bf16(acc[2] * sc, acc[3] * sc);
  o.z = pk_bf16(acc[4] * sc, acc[5] * sc); o.w = pk_bf16(acc[6] * sc, acc[7] * sc);
  const int d = g >> 3, r = g & 7;
  __builtin_nontemporal_store(o, (u32x4*)&agg[((size_t)r * PADN + d) * 64 + lane * 4]);
}

// ---------------- layer-1 MFMA GEMM (contiguous relation-major A planes) ----------------
__global__ __launch_bounds__(256)
void rgcn_gemm_mfma(const unsigned short* __restrict__ agg,   // [8][PADN][128] bf16
                    const unsigned short* __restrict__ xrow,  // [PADN][128] bf16
                    const unsigned short* __restrict__ Wt,    // [9][128][128] bf16
                    const float* __restrict__ bias,
                    unsigned short* __restrict__ Cout) {
  constexpr int BN = 128, WM = 64, MF = 4, NF = 4, WAVES_N = 2;
  __shared__ uint4 ldsv[(128 * 128 + BN * 128) / 16];
  char* As = (char*)ldsv;
  char* Bs = (char*)ldsv + 128 * 128;

  const int t = threadIdx.x;
  const int l = t & 63;
  const int w = t >> 6;
  const int wr = w / WAVES_N;
  const int wc = w % WAVES_N;
  const int row0 = blockIdx.x * 128;
  const int l15 = l & 15, lq = l >> 4;

  f32x4 acc[MF][NF];
#pragma unroll
  for (int mi = 0; mi < MF; ++mi)
#pragma unroll
    for (int ni = 0; ni < NF; ++ni) acc[mi][ni] = (f32x4){0.f, 0.f, 0.f, 0.f};

  for (int ch = 0; ch < 9; ++ch) {
    const unsigned short* aP = (ch < 8) ? (agg + (size_t)ch * PADN * KD) : xrow;
    const unsigned short* bP = Wt + (size_t)ch * BN * KD;
#pragma unroll
    for (int kt = 0; kt < 2; ++kt) {
      __syncthreads();
#pragma unroll
      for (int i = 0; i < 4; ++i) {
        const int s = t + i * 256;
        const int r = s >> 3, c16 = s & 7;
        u32x4 v = __builtin_nontemporal_load(
            (const u32x4*)(aP + (size_t)(row0 + r) * KD + kt * 64 + c16 * 8));
        *(u32x4*)(As + r * 128 + ((c16 ^ (r & 7)) * 16)) = v;
      }
#pragma unroll
      for (int i = 0; i < BN / 32; ++i) {
        const int s = t + i * 256;
        const int r = s >> 3, c16 = s & 7;
        uint4 v = *(const uint4*)(bP + (size_t)r * KD + kt * 64 + c16 * 8);
        *(uint4*)(Bs + r * 128 + ((c16 ^ (r & 7)) * 16)) = v;
      }
      __syncthreads();
#pragma unroll
      for (int ks = 0; ks < 2; ++ks) {
        short8 bfr[NF];
#pragma unroll
        for (int ni = 0; ni < NF; ++ni) {
          const int br = wc * 64 + ni * 16 + l15;
          bfr[ni] = *(const short8*)(Bs + br * 128 + (((ks * 4 + lq) ^ (br & 7)) * 16));
        }
#pragma unroll
        for (int mi = 0; mi < MF; ++mi) {
          const int ar = wr * WM + mi * 16 + l15;
          short8 af = *(const short8*)(As + ar * 128 + (((ks * 4 + lq) ^ (ar & 7)) * 16));
#pragma unroll
          for (int ni = 0; ni < NF; ++ni)
            acc[mi][ni] = __builtin_amdgcn_mfma_f32_16x16x32_bf16(af, bfr[ni], acc[mi][ni], 0, 0, 0);
        }
      }
    }
  }
#pragma unroll
  for (int ni = 0; ni < NF; ++ni) {
    const int col = wc * 64 + ni * 16 + l15;
    const float bv = bias[col];
#pragma unroll
    for (int mi = 0; mi < MF; ++mi) {
#pragma unroll
      for (int q = 0; q < 4; ++q) {
        const int grow = row0 + wr * WM + mi * 16 + lq * 4 + q;
        if (grow < NN) {
          float v = fmaxf(acc[mi][ni][q] + bv, 0.f);
          Cout[(size_t)grow * BN + col] = bf1(v);
        } else {
          Cout[(size_t)grow * BN + col] = 0;   // clean pad rows for gemm_y
        }
      }
    }
  }
}

// ---------------- layer-2 transform GEMM: Y[M,576] = hb[M,128] @ Wt2^T ----------------
__global__ __launch_bounds__(256)
void gemm_y(const unsigned short* __restrict__ A,    // [PADN][128] bf16
            const unsigned short* __restrict__ Wt,   // [576][128] bf16
            unsigned short* __restrict__ Y) {        // [PADN][576] bf16
  constexpr int BN = 64, NCOLS = 576, WM = 32, MF = 2, NF = 4;
  __shared__ uint4 ldsv[(128 * 128 + BN * 128) / 16];
  char* As = (char*)ldsv;
  char* Bs = (char*)ldsv + 128 * 128;

  const int t = threadIdx.x;
  const int l = t & 63;
  const int w = t >> 6;
  const int row0 = blockIdx.x * 128;
  const int col0 = blockIdx.y * BN;
  const unsigned short* bP = Wt + (size_t)col0 * KD;
  const int l15 = l & 15, lq = l >> 4;

  f32x4 acc[MF][NF];
#pragma unroll
  for (int mi = 0; mi < MF; ++mi)
#pragma unroll
    for (int ni = 0; ni < NF; ++ni) acc[mi][ni] = (f32x4){0.f, 0.f, 0.f, 0.f};

#pragma unroll
  for (int kt = 0; kt < 2; ++kt) {
    __syncthreads();
#pragma unroll
    for (int i = 0; i < 4; ++i) {
      const int s = t + i * 256;
      const int r = s >> 3, c16 = s & 7;
      uint4 v = *(const uint4*)(A + (size_t)(row0 + r) * KD + kt * 64 + c16 * 8);
      *(uint4*)(As + r * 128 + ((c16 ^ (r & 7)) * 16)) = v;
    }
#pragma unroll
    for (int i = 0; i < BN / 32; ++i) {
      const int s = t + i * 256;
      const int r = s >> 3, c16 = s & 7;
      uint4 v = *(const uint4*)(bP + (size_t)r * KD + kt * 64 + c16 * 8);
      *(uint4*)(Bs + r * 128 + ((c16 ^ (r & 7)) * 16)) = v;
    }
    __syncthreads();
#pragma unroll
    for (int ks = 0; ks < 2; ++ks) {
      short8 bfr[NF];
#pragma unroll
      for (int ni = 0; ni < NF; ++ni) {
        const int br = ni * 16 + l15;
        bfr[ni] = *(const short8*)(Bs + br * 128 + (((ks * 4 + lq) ^ (br & 7)) * 16));
      }
#pragma unroll
      for (int mi = 0; mi < MF; ++mi) {
        const int ar = w * WM + mi * 16 + l15;
        short8 af = *(const short8*)(As + ar * 128 + (((ks * 4 + lq) ^ (ar & 7)) * 16));
#pragma unroll
        for (int ni = 0; ni < NF; ++ni)
          acc[mi][ni] = __builtin_amdgcn_mfma_f32_16x16x32_bf16(af, bfr[ni], acc[mi][ni], 0, 0, 0);
      }
    }
  }
#pragma unroll
  for (int ni = 0; ni < NF; ++ni) {
    const int col = col0 + ni * 16 + l15;
#pragma unroll
    for (int mi = 0; mi < MF; ++mi) {
#pragma unroll
      for (int q = 0; q < 4; ++q) {
        const int grow = row0 + w * WM + mi * 16 + lq * 4 + q;
        Y[(size_t)grow * NCOLS + col] = bf1(acc[mi][ni][q]);
      }
    }
  }
}

// ---------------- layer-2 gather-reduce: out[d] = self + bias + sum_r mean_r ----
__global__ __launch_bounds__(256)
void gather_out(const unsigned* __restrict__ Y,      // [PADN][288] uints
                const int* __restrict__ srt,
                const int* __restrict__ fillpos, const int* __restrict__ cntarr,
                const float* __restrict__ bias,
                float* __restrict__ Out) {
  const int d = blockIdx.x * 16 + (threadIdx.x >> 4);
  const int lane = threadIdx.x & 15;
  const int l = threadIdx.x & 63;
  const int g16 = l & 48;

  const int meta = (lane < 8) ? fillpos[d * 8 + lane] : cntarr[d * 8 + (lane - 8)];

  float acc[4] = {};
#pragma unroll
  for (int r = 0; r < 8; ++r) {
    const int base = __shfl(meta, g16 + r);
    const int c    = __shfl(meta, g16 + 8 + r);
    float tmp[4] = {};
    int i = 0;
    for (; i + 1 < c; i += 2) {
      const int s0 = srt[base + i], s1 = srt[base + i + 1];
      const uint2 v0 = *(const uint2*)&Y[(size_t)s0 * 288 + r * 32 + lane * 2];
      const uint2 v1 = *(const uint2*)&Y[(size_t)s1 * 288 + r * 32 + lane * 2];
      tmp[0] += bflo(v0.x) + bflo(v1.x); tmp[1] += bfhi(v0.x) + bfhi(v1.x);
      tmp[2] += bflo(v0.y) + bflo(v1.y); tmp[3] += bfhi(v0.y) + bfhi(v1.y);
    }
    if (i < c) {
      const uint2 v0 = *(const uint2*)&Y[(size_t)srt[base + i] * 288 + r * 32 + lane * 2];
      tmp[0] += bflo(v0.x); tmp[1] += bfhi(v0.x);
      tmp[2] += bflo(v0.y); tmp[3] += bfhi(v0.y);
    }
    const float inv = (c > 0) ? 1.0f / (float)c : 0.0f;
#pragma unroll
    for (int j = 0; j < 4; ++j) acc[j] += tmp[j] * inv;
  }

  const uint2 sv = *(const uint2*)&Y[(size_t)d * 288 + 256 + lane * 2];
  const float4 b0 = *(const float4*)&bias[lane * 4];
  float4 o;
  o.x = bflo(sv.x) + b0.x + acc[0];
  o.y = bfhi(sv.x) + b0.y + acc[1];
  o.z = bflo(sv.y) + b0.z + acc[2];
  o.w = bfhi(sv.y) + b0.w + acc[3];
  *(float4*)&Out[(size_t)d * 64 + lane * 4] = o;
}

// ---------------- launch ----------------
extern "C" void kernel_launch(void* const* d_in, const int* in_sizes, int n_in,
                              void* d_out, int out_size, void* d_ws, size_t ws_size,
                              hipStream_t stream) {
  const float* x     = (const float*)d_in[0];
  const int*   ei    = (const int*)d_in[1];
  const int*   et    = (const int*)d_in[2];
  const float* W1    = (const float*)d_in[3];
  const float* root1 = (const float*)d_in[4];
  const float* b1    = (const float*)d_in[5];
  const float* W2    = (const float*)d_in[6];
  const float* root2 = (const float*)d_in[7];
  const float* b2    = (const float*)d_in[8];
  float* out = (float*)d_out;

  const int E = in_sizes[2];
  const int* src  = ei;
  const int* dstv = ei + E;

  // workspace layout (~135.5 MB, 16B-aligned)
  char* ws = (char*)d_ws;
  unsigned short* xb  = (unsigned short*)ws;                 // 12,812,288 B
  unsigned short* hb  = (unsigned short*)(ws + 12812288);    // 12,812,288 B
  unsigned short* agg = (unsigned short*)(ws + 25624576);    // 102,498,304 B (ebuf/Y2 alias)
  unsigned short* Wt1 = (unsigned short*)(ws + 128122880);   //    294,912 B
  unsigned short* Wt2 = (unsigned short*)(ws + 128417792);   //    147,456 B
  int* fillpos = (int*)(ws + 128565248);                     // PADSEG*4 = 1,605,632 B
  int* cntarr  = (int*)(ws + 130170880);                     // PADSEG*4 = 1,605,632 B
  int* srt     = (int*)(ws + 131776512);                     //  3,200,000 B
  int* hist    = (int*)(ws + 134976512);                     //    524,288 B (256*NBE*4)
  int* bktBase = (int*)(ws + 135500800);                     //      1,024 B
  int* bktCnt  = (int*)(ws + 135501824);                     //      1,024 B
  uint2* ebuf  = (uint2*)agg;   // 6.4 MB, dead before agg is written

  const int NBE = (E + 2047) / 2048;   // 392 for E=800000

  // structure build: hist -> scan -> partition -> per-bucket build (no global atomics)
  convert_x<<<PADN * 16 / 256, 256, 0, stream>>>(x, (unsigned*)xb);
  p1_hist<<<NBE, 256, 0, stream>>>(dstv, E, NBE, hist);
  p2_scan<<<1, 256, 0, stream>>>(hist, NBE, bktBase, bktCnt);
  p3_part<<<NBE, 256, 0, stream>>>(src, dstv, et, E, NBE, hist, ebuf);
  p4_build<<<NBKT, 256, 0, stream>>>(ebuf, bktBase, bktCnt, fillpos, cntarr, srt);

  prep_w<<<(9 * 128 * KD + 9 * 64 * KD) / 256, 256, 0, stream>>>(W1, root1, W2, root2, Wt1, Wt2);

  const int mBlocks = PADN / 128;       // 391

  // layer 1: aggregate-then-transform (relation-major agg)
  gather_mean<<<NSEG / 16, 256, 0, stream>>>((const unsigned*)xb, srt, fillpos, cntarr, (unsigned*)agg);
  rgcn_gemm_mfma<<<mBlocks, 256, 0, stream>>>(agg, xb, Wt1, b1, hb);

  // layer 2: transform-then-aggregate (Y path, straight to out)
  unsigned short* Y2 = agg;
  gemm_y<<<dim3(mBlocks, 9), 256, 0, stream>>>(hb, Wt2, Y2);
  gather_out<<<NN / 16, 256, 0, stream>>>((const unsigned*)Y2, srt, fillpos, cntarr, b2, out);
}

// Round 13
// 214.499 us; speedup vs baseline: 1.0836x; 1.0749x over previous
//
#include <hip/hip_runtime.h>

constexpr int NN   = 50000;
constexpr int PADN = 50048;       // 391*128, padded rows
constexpr int KD   = 128;
constexpr int RR   = 8;
constexpr int NSEG = RR * NN;     // 400000
constexpr int NBLK = 196;         // scan blocks: 196*2048 = 401408 >= NSEG
constexpr int PADSEG = NBLK * 2048;
// segment order: segidx(r,d) = 2*((r>>1)*NN + d) + (r&1)
// packed counters: cntp[(r>>1)*NN + d], 16-bit field (r&1)

typedef __attribute__((ext_vector_type(8))) short short8;
typedef __attribute__((ext_vector_type(4))) float f32x4;
typedef __attribute__((ext_vector_type(4))) unsigned int u32x4;

__device__ __forceinline__ float bflo(unsigned u){ return __uint_as_float(u << 16); }
__device__ __forceinline__ float bfhi(unsigned u){ return __uint_as_float(u & 0xffff0000u); }
__device__ __forceinline__ unsigned pk_bf16(float a, float b){
  unsigned ua = __float_as_uint(a), ub = __float_as_uint(b);
  ua = (ua + 0x7fffu + ((ua >> 16) & 1u)) >> 16;
  ub = (ub + 0x7fffu + ((ub >> 16) & 1u)) & 0xffff0000u;
  return (ua & 0xffffu) | ub;
}
__device__ __forceinline__ unsigned short bf1(float a){
  unsigned ua = __float_as_uint(a);
  return (unsigned short)((ua + 0x7fffu + ((ua >> 16) & 1u)) >> 16);
}

// ---------------- pass 1: convert x to bf16 + packed rank-assign ----------------
__global__ __launch_bounds__(256)
void convert_count_rank(const float* __restrict__ x, unsigned* __restrict__ xb,
                        const int* __restrict__ dst, const int* __restrict__ et,
                        int E, unsigned* __restrict__ cntp, int* __restrict__ rank) {
  const int idx = blockIdx.x * 256 + threadIdx.x;
  if (idx < E) {
    const int r = et[idx], d = dst[idx];
    const int sh = (r & 1) * 16;
    const unsigned old = atomicAdd(&cntp[(r >> 1) * NN + d], 1u << sh);
    rank[idx] = (old >> sh) & 0xffffu;
  }
  if (idx < PADN * 16) {
    const int row = idx >> 4, o = (idx & 15) * 8;
    uint4 v = make_uint4(0u, 0u, 0u, 0u);
    if (row < NN) {
      float4 a = *(const float4*)&x[(size_t)row * KD + o];
      float4 b = *(const float4*)&x[(size_t)row * KD + o + 4];
      v.x = pk_bf16(a.x, a.y); v.y = pk_bf16(a.z, a.w);
      v.z = pk_bf16(b.x, b.y); v.w = pk_bf16(b.z, b.w);
    }
    *(uint4*)&xb[(size_t)idx * 4] = v;
  }
}

// hierarchical exclusive scan over segidx order; reads PACKED counters.
__global__ __launch_bounds__(256)
void scan_block(const unsigned* __restrict__ cntp, int* __restrict__ fillpos,
                int* __restrict__ blkSum) {
  const int t = threadIdx.x;
  const int wbase = blockIdx.x * 1024 + t * 4;     // packed-word index
  const uint4 wv = *(const uint4*)&cntp[wbase];
  int s8[8];
  s8[0] = wv.x & 0xffff; s8[1] = wv.x >> 16;
  s8[2] = wv.y & 0xffff; s8[3] = wv.y >> 16;
  s8[4] = wv.z & 0xffff; s8[5] = wv.z >> 16;
  s8[6] = wv.w & 0xffff; s8[7] = wv.w >> 16;
  int tsum = 0;
#pragma unroll
  for (int i = 0; i < 8; ++i) tsum += s8[i];
  int inc = tsum;
#pragma unroll
  for (int o = 1; o < 64; o <<= 1) {
    int v = __shfl_up(inc, o);
    if ((t & 63) >= o) inc += v;
  }
  __shared__ int wsum[4];
  if ((t & 63) == 63) wsum[t >> 6] = inc;
  __syncthreads();
  int wpre = 0;
#pragma unroll
  for (int w = 0; w < 4; ++w) if (w < (t >> 6)) wpre += wsum[w];
  int run = wpre + inc - tsum;
  int o8[8];
#pragma unroll
  for (int i = 0; i < 8; ++i) { o8[i] = run; run += s8[i]; }
  const int base = wbase * 2;   // segment index
  *(int4*)&fillpos[base]     = make_int4(o8[0], o8[1], o8[2], o8[3]);
  *(int4*)&fillpos[base + 4] = make_int4(o8[4], o8[5], o8[6], o8[7]);
  if (t == 255) blkSum[blockIdx.x] = wpre + inc;
}

__global__ __launch_bounds__(256)
void scan_tops(int* __restrict__ blkSum) {
  const int t = threadIdx.x;
  const int v = (t < NBLK) ? blkSum[t] : 0;
  int inc = v;
#pragma unroll
  for (int o = 1; o < 64; o <<= 1) {
    int u = __shfl_up(inc, o);
    if ((t & 63) >= o) inc += u;
  }
  __shared__ int wsum[4];
  if ((t & 63) == 63) wsum[t >> 6] = inc;
  __syncthreads();
  int wpre = 0;
#pragma unroll
  for (int w = 0; w < 4; ++w) if (w < (t >> 6)) wpre += wsum[w];
  if (t < NBLK) blkSum[t] = wpre + inc - v;
}

__global__ __launch_bounds__(256)
void scan_apply(int* __restrict__ fillpos, const int* __restrict__ blkSum) {
  const int base = blockIdx.x * 2048 + threadIdx.x * 8;
  const int off = blkSum[blockIdx.x];
  int4 a = *(int4*)&fillpos[base];
  int4 b = *(int4*)&fillpos[base + 4];
  a.x += off; a.y += off; a.z += off; a.w += off;
  b.x += off; b.y += off; b.z += off; b.w += off;
  *(int4*)&fillpos[base]     = a;
  *(int4*)&fillpos[base + 4] = b;
}

// ---------------- pass 2: scatter srcs to sorted order, NO atomics ----------------
__global__ __launch_bounds__(256)
void fill_scatter(const int* __restrict__ src, const int* __restrict__ dst,
                  const int* __restrict__ et, const int* __restrict__ rank,
                  int E, const int* __restrict__ segbase, int* __restrict__ srt) {
  const int e = blockIdx.x * 256 + threadIdx.x;
  if (e < E) {
    const int r = et[e];
    const int seg = 2 * ((r >> 1) * NN + dst[e]) + (r & 1);
    srt[segbase[seg] + rank[e]] = src[e];
  }
}

// Wt1[9][128][128] and Wt2[9][64][128] bf16, transposed, in one dispatch
__global__ __launch_bounds__(256)
void prep_w(const float* __restrict__ W1, const float* __restrict__ root1,
            const float* __restrict__ W2, const float* __restrict__ root2,
            unsigned short* __restrict__ Wt1, unsigned short* __restrict__ Wt2) {
  int idx = blockIdx.x * 256 + threadIdx.x;
  if (idx < 9 * 128 * KD) {
    const int k = idx & 127;
    const int n = (idx >> 7) & 127;
    const int ch = idx >> 14;
    const float v = (ch < 8) ? W1[((size_t)ch * KD + k) * 128 + n] : root1[(size_t)k * 128 + n];
    Wt1[idx] = bf1(v);
  } else {
    idx -= 9 * 128 * KD;
    const int k = idx & 127;
    const int n = (idx >> 7) & 63;
    const int ch = idx >> 13;
    const float v = (ch < 8) ? W2[((size_t)ch * KD + k) * 64 + n] : root2[(size_t)k * 64 + n];
    Wt2[idx] = bf1(v);
  }
}

// ---------------- layer-1 gather: agg[r][d][:] = mean of bf16 X rows ----------------
__global__ __launch_bounds__(256)
void gather_mean(const unsigned* __restrict__ Xb,         // [PADN][64] uint
                 const int* __restrict__ srt,
                 const int* __restrict__ segbase, const unsigned* __restrict__ cntp,
                 unsigned* __restrict__ agg) {            // [8][PADN][64] uint
  const int g = blockIdx.x * 16 + (threadIdx.x >> 4);     // segidx
  const int lane = threadIdx.x & 15;
  const int word = g >> 1, bit = g & 1;
  const int c = (cntp[word] >> (bit * 16)) & 0xffff;
  const int base = segbase[g];
  float acc[8] = {};
  int i = 0;
  for (; i + 1 < c; i += 2) {
    const int s0 = srt[base + i], s1 = srt[base + i + 1];
    const uint4 v0 = *(const uint4*)&Xb[(size_t)s0 * 64 + lane * 4];
    const uint4 v1 = *(const uint4*)&Xb[(size_t)s1 * 64 + lane * 4];
    acc[0] += bflo(v0.x) + bflo(v1.x); acc[1] += bfhi(v0.x) + bfhi(v1.x);
    acc[2] += bflo(v0.y) + bflo(v1.y); acc[3] += bfhi(v0.y) + bfhi(v1.y);
    acc[4] += bflo(v0.z) + bflo(v1.z); acc[5] += bfhi(v0.z) + bfhi(v1.z);
    acc[6] += bflo(v0.w) + bflo(v1.w); acc[7] += bfhi(v0.w) + bfhi(v1.w);
  }
  if (i < c) {
    const uint4 v0 = *(const uint4*)&Xb[(size_t)srt[base + i] * 64 + lane * 4];
    acc[0] += bflo(v0.x); acc[1] += bfhi(v0.x);
    acc[2] += bflo(v0.y); acc[3] += bfhi(v0.y);
    acc[4] += bflo(v0.z); acc[5] += bfhi(v0.z);
    acc[6] += bflo(v0.w); acc[7] += bfhi(v0.w);
  }
  const float sc = (c > 0) ? 1.0f / (float)c : 0.0f;
  u32x4 o;
  o.x = pk_bf16(acc[0] * sc, acc[1] * sc); o.y = pk_bf16(acc[2] * sc, acc[3] * sc);
  o.z = pk_bf16(acc[4] * sc, acc[5] * sc); o.w = pk_bf16(acc[6] * sc, acc[7] * sc);
  const int q = word / NN, d = word - q * NN;
  const int r = q * 2 + bit;
  __builtin_nontemporal_store(o, (u32x4*)&agg[((size_t)r * PADN + d) * 64 + lane * 4]);
}

// ---------------- layer-1 MFMA GEMM ----------------
__global__ __launch_bounds__(256)
void rgcn_gemm_mfma(const unsigned short* __restrict__ agg,   // [8][PADN][128] bf16
                    const unsigned short* __restrict__ xrow,  // [PADN][128] bf16
                    const unsigned short* __restrict__ Wt,    // [9][128][128] bf16
                    const float* __restrict__ bias,
                    unsigned short* __restrict__ Cout) {
  constexpr int BN = 128, WM = 64, MF = 4, NF = 4, WAVES_N = 2;
  __shared__ uint4 ldsv[(128 * 128 + BN * 128) / 16];
  char* As = (char*)ldsv;
  char* Bs = (char*)ldsv + 128 * 128;

  const int t = threadIdx.x;
  const int l = t & 63;
  const int w = t >> 6;
  const int wr = w / WAVES_N;
  const int wc = w % WAVES_N;
  const int row0 = blockIdx.x * 128;
  const int l15 = l & 15, lq = l >> 4;

  f32x4 acc[MF][NF];
#pragma unroll
  for (int mi = 0; mi < MF; ++mi)
#pragma unroll
    for (int ni = 0; ni < NF; ++ni) acc[mi][ni] = (f32x4){0.f, 0.f, 0.f, 0.f};

  for (int ch = 0; ch < 9; ++ch) {
    const unsigned short* aP = (ch < 8) ? (agg + (size_t)ch * PADN * KD) : xrow;
    const unsigned short* bP = Wt + (size_t)ch * BN * KD;
#pragma unroll
    for (int kt = 0; kt < 2; ++kt) {
      __syncthreads();
#pragma unroll
      for (int i = 0; i < 4; ++i) {
        const int s = t + i * 256;
        const int r = s >> 3, c16 = s & 7;
        u32x4 v = __builtin_nontemporal_load(
            (const u32x4*)(aP + (size_t)(row0 + r) * KD + kt * 64 + c16 * 8));
        *(u32x4*)(As + r * 128 + ((c16 ^ (r & 7)) * 16)) = v;
      }
#pragma unroll
      for (int i = 0; i < BN / 32; ++i) {
        const int s = t + i * 256;
        const int r = s >> 3, c16 = s & 7;
        uint4 v = *(const uint4*)(bP + (size_t)r * KD + kt * 64 + c16 * 8);
        *(uint4*)(Bs + r * 128 + ((c16 ^ (r & 7)) * 16)) = v;
      }
      __syncthreads();
#pragma unroll
      for (int ks = 0; ks < 2; ++ks) {
        short8 bfr[NF];
#pragma unroll
        for (int ni = 0; ni < NF; ++ni) {
          const int br = wc * 64 + ni * 16 + l15;
          bfr[ni] = *(const short8*)(Bs + br * 128 + (((ks * 4 + lq) ^ (br & 7)) * 16));
        }
#pragma unroll
        for (int mi = 0; mi < MF; ++mi) {
          const int ar = wr * WM + mi * 16 + l15;
          short8 af = *(const short8*)(As + ar * 128 + (((ks * 4 + lq) ^ (ar & 7)) * 16));
#pragma unroll
          for (int ni = 0; ni < NF; ++ni)
            acc[mi][ni] = __builtin_amdgcn_mfma_f32_16x16x32_bf16(af, bfr[ni], acc[mi][ni], 0, 0, 0);
        }
      }
    }
  }
#pragma unroll
  for (int ni = 0; ni < NF; ++ni) {
    const int col = wc * 64 + ni * 16 + l15;
    const float bv = bias[col];
#pragma unroll
    for (int mi = 0; mi < MF; ++mi) {
#pragma unroll
      for (int q = 0; q < 4; ++q) {
        const int grow = row0 + wr * WM + mi * 16 + lq * 4 + q;
        if (grow < NN) {
          float v = fmaxf(acc[mi][ni][q] + bv, 0.f);
          Cout[(size_t)grow * BN + col] = bf1(v);
        } else {
          Cout[(size_t)grow * BN + col] = 0;   // clean pad rows for gemm_y
        }
      }
    }
  }
}

// ---------------- layer-2 transform GEMM: Y[M,576] = hb[M,128] @ Wt2^T ----------------
__global__ __launch_bounds__(256)
void gemm_y(const unsigned short* __restrict__ A,    // [PADN][128] bf16
            const unsigned short* __restrict__ Wt,   // [576][128] bf16
            unsigned short* __restrict__ Y) {        // [PADN][576] bf16
  constexpr int BN = 64, NCOLS = 576, WM = 32, MF = 2, NF = 4;
  __shared__ uint4 ldsv[(128 * 128 + BN * 128) / 16];
  char* As = (char*)ldsv;
  char* Bs = (char*)ldsv + 128 * 128;

  const int t = threadIdx.x;
  const int l = t & 63;
  const int w = t >> 6;
  const int row0 = blockIdx.x * 128;
  const int col0 = blockIdx.y * BN;
  const unsigned short* bP = Wt + (size_t)col0 * KD;
  const int l15 = l & 15, lq = l >> 4;

  f32x4 acc[MF][NF];
#pragma unroll
  for (int mi = 0; mi < MF; ++mi)
#pragma unroll
    for (int ni = 0; ni < NF; ++ni) acc[mi][ni] = (f32x4){0.f, 0.f, 0.f, 0.f};

#pragma unroll
  for (int kt = 0; kt < 2; ++kt) {
    __syncthreads();
#pragma unroll
    for (int i = 0; i < 4; ++i) {
      const int s = t + i * 256;
      const int r = s >> 3, c16 = s & 7;
      uint4 v = *(const uint4*)(A + (size_t)(row0 + r) * KD + kt * 64 + c16 * 8);
      *(uint4*)(As + r * 128 + ((c16 ^ (r & 7)) * 16)) = v;
    }
#pragma unroll
    for (int i = 0; i < BN / 32; ++i) {
      const int s = t + i * 256;
      const int r = s >> 3, c16 = s & 7;
      uint4 v = *(const uint4*)(bP + (size_t)r * KD + kt * 64 + c16 * 8);
      *(uint4*)(Bs + r * 128 + ((c16 ^ (r & 7)) * 16)) = v;
    }
    __syncthreads();
#pragma unroll
    for (int ks = 0; ks < 2; ++ks) {
      short8 bfr[NF];
#pragma unroll
      for (int ni = 0; ni < NF; ++ni) {
        const int br = ni * 16 + l15;
        bfr[ni] = *(const short8*)(Bs + br * 128 + (((ks * 4 + lq) ^ (br & 7)) * 16));
      }
#pragma unroll
      for (int mi = 0; mi < MF; ++mi) {
        const int ar = w * WM + mi * 16 + l15;
        short8 af = *(const short8*)(As + ar * 128 + (((ks * 4 + lq) ^ (ar & 7)) * 16));
#pragma unroll
        for (int ni = 0; ni < NF; ++ni)
          acc[mi][ni] = __builtin_amdgcn_mfma_f32_16x16x32_bf16(af, bfr[ni], acc[mi][ni], 0, 0, 0);
      }
    }
  }
#pragma unroll
  for (int ni = 0; ni < NF; ++ni) {
    const int col = col0 + ni * 16 + l15;
#pragma unroll
    for (int mi = 0; mi < MF; ++mi) {
#pragma unroll
      for (int q = 0; q < 4; ++q) {
        const int grow = row0 + w * WM + mi * 16 + lq * 4 + q;
        Y[(size_t)grow * NCOLS + col] = bf1(acc[mi][ni][q]);
      }
    }
  }
}

// ---------------- layer-2 gather-reduce: out[d] = self + bias + sum_r mean_r ----
__global__ __launch_bounds__(256)
void gather_out(const unsigned* __restrict__ Y,      // [PADN][288] uints
                const int* __restrict__ srt,
                const int* __restrict__ segbase, const unsigned* __restrict__ cntp,
                const float* __restrict__ bias,
                float* __restrict__ Out) {
  const int d = blockIdx.x * 16 + (threadIdx.x >> 4);
  const int lane = threadIdx.x & 15;
  const int l = threadIdx.x & 63;

  int meta = 0;
  if (lane < 8) {
    meta = (cntp[(lane >> 1) * NN + d] >> ((lane & 1) * 16)) & 0xffff;
  } else {
    const int rr = lane - 8;
    meta = segbase[2 * ((rr >> 1) * NN + d) + (rr & 1)];
  }

  float acc[4] = {};
#pragma unroll
  for (int r = 0; r < 8; ++r) {
    const int c    = __shfl(meta, (l & 48) + r);
    const int base = __shfl(meta, (l & 48) + 8 + r);
    float tmp[4] = {};
    int i = 0;
    for (; i + 1 < c; i += 2) {
      const int s0 = srt[base + i], s1 = srt[base + i + 1];
      const uint2 v0 = *(const uint2*)&Y[(size_t)s0 * 288 + r * 32 + lane * 2];
      const uint2 v1 = *(const uint2*)&Y[(size_t)s1 * 288 + r * 32 + lane * 2];
      tmp[0] += bflo(v0.x) + bflo(v1.x); tmp[1] += bfhi(v0.x) + bfhi(v1.x);
      tmp[2] += bflo(v0.y) + bflo(v1.y); tmp[3] += bfhi(v0.y) + bfhi(v1.y);
    }
    if (i < c) {
      const uint2 v0 = *(const uint2*)&Y[(size_t)srt[base + i] * 288 + r * 32 + lane * 2];
      tmp[0] += bflo(v0.x); tmp[1] += bfhi(v0.x);
      tmp[2] += bflo(v0.y); tmp[3] += bfhi(v0.y);
    }
    const float inv = (c > 0) ? 1.0f / (float)c : 0.0f;
#pragma unroll
    for (int j = 0; j < 4; ++j) acc[j] += tmp[j] * inv;
  }

  // self slice (ch 8) + bias
  const uint2 sv = *(const uint2*)&Y[(size_t)d * 288 + 256 + lane * 2];
  const float4 b0 = *(const float4*)&bias[lane * 4];
  float4 o;
  o.x = bflo(sv.x) + b0.x + acc[0];
  o.y = bfhi(sv.x) + b0.y + acc[1];
  o.z = bflo(sv.y) + b0.z + acc[2];
  o.w = bfhi(sv.y) + b0.w + acc[3];
  *(float4*)&Out[(size_t)d * 64 + lane * 4] = o;
}

// ---------------- launch ----------------
extern "C" void kernel_launch(void* const* d_in, const int* in_sizes, int n_in,
                              void* d_out, int out_size, void* d_ws, size_t ws_size,
                              hipStream_t stream) {
  const float* x     = (const float*)d_in[0];
  const int*   ei    = (const int*)d_in[1];
  const int*   et    = (const int*)d_in[2];
  const float* W1    = (const float*)d_in[3];
  const float* root1 = (const float*)d_in[4];
  const float* b1    = (const float*)d_in[5];
  const float* W2    = (const float*)d_in[6];
  const float* root2 = (const float*)d_in[7];
  const float* b2    = (const float*)d_in[8];
  float* out = (float*)d_out;

  const int E = in_sizes[2];
  const int* src  = ei;
  const int* dstv = ei + E;

  // workspace layout (~135 MB, 16B-aligned)
  char* ws = (char*)d_ws;
  unsigned short* xb  = (unsigned short*)ws;                 // 12,812,288 B
  unsigned short* hb  = (unsigned short*)(ws + 12812288);    // 12,812,288 B
  unsigned short* agg = (unsigned short*)(ws + 25624576);    // 102,498,304 B (agg / Y2 / rank)
  unsigned short* Wt1 = (unsigned short*)(ws + 128122880);   //    294,912 B
  unsigned short* Wt2 = (unsigned short*)(ws + 128417792);   //    147,456 B
  unsigned* cntp = (unsigned*)(ws + 128565248);              // PADSEG/2*4 = 802,816 B
  int* fillpos = (int*)(ws + 130170880);                     // PADSEG*4 = 1,605,632 B
  int* blkSum  = (int*)(ws + 131776512);                     //      1,024 B
  int* srt     = (int*)(ws + 131777536);                     //  3,200,000 B
  int* rank    = (int*)agg;       // consumed by fill_scatter before agg written
  unsigned short* Y2 = agg;       // layer-2 Y aliases agg (agg dead after gemm1)

  // structure build: packed rank-assign (+x convert) -> scan -> scatter
  hipMemsetAsync(cntp, 0, sizeof(unsigned) * (size_t)(PADSEG / 2), stream);
  convert_count_rank<<<PADN * 16 / 256, 256, 0, stream>>>(x, (unsigned*)xb, dstv, et, E, cntp, rank);
  scan_block<<<NBLK, 256, 0, stream>>>(cntp, fillpos, blkSum);
  scan_tops<<<1, 256, 0, stream>>>(blkSum);
  scan_apply<<<NBLK, 256, 0, stream>>>(fillpos, blkSum);
  fill_scatter<<<(E + 255) / 256, 256, 0, stream>>>(src, dstv, et, rank, E, fillpos, srt);

  prep_w<<<(9 * 128 * KD + 9 * 64 * KD) / 256, 256, 0, stream>>>(W1, root1, W2, root2, Wt1, Wt2);

  const int mBlocks = PADN / 128;       // 391

  // layer 1: aggregate-then-transform (agg path)
  gather_mean<<<NSEG / 16, 256, 0, stream>>>((const unsigned*)xb, srt, fillpos, cntp, (unsigned*)agg);
  rgcn_gemm_mfma<<<mBlocks, 256, 0, stream>>>(agg, xb, Wt1, b1, hb);

  // layer 2: transform-then-aggregate (Y path, straight to out)
  gemm_y<<<dim3(mBlocks, 9), 256, 0, stream>>>(hb, Wt2, Y2);
  gather_out<<<NN / 16, 256, 0, stream>>>((const unsigned*)Y2, srt, fillpos, cntp, b2, out);
}